// Round 22
// baseline (99.500 us; speedup 1.0000x reference)
//
#include <hip/hip_runtime.h>
#include <math.h>

#define LOG2E_F 1.4426950408889634f
#define LN2_F   0.6931471805599453f

constexpr int Bn = 1024;
constexpr int Tn = 512;
constexpr int Ln = 32;

typedef unsigned int uint2v __attribute__((ext_vector_type(2)));

// ---- cross-lane swaps (runtime-probed mapping, VALU permlane ops) ----------
#if __has_builtin(__builtin_amdgcn_permlane32_swap)
#define PROBE32 \
    bool use_y32; \
    { \
        const uint2v r = __builtin_amdgcn_permlane32_swap((unsigned)l, (unsigned)l, false, false); \
        const bool selA = __all((((l < 32) ? (int)r[1] : (int)r[0]) == (l ^ 32)) ? 1 : 0); \
        use_y32 = selA ? (l < 32) : (l >= 32); \
    }
#define CROSS32(p, out) { \
    const uint2v r_ = __builtin_amdgcn_permlane32_swap( \
        __float_as_uint(p), __float_as_uint(p), false, false); \
    out = __uint_as_float(use_y32 ? r_[1] : r_[0]); }
#else
#define PROBE32
#define CROSS32(p, out) out = __shfl_xor((p), 32);
#endif

#if __has_builtin(__builtin_amdgcn_permlane16_swap)
#define PROBE16 \
    bool use_r016; \
    { \
        const uint2v r = __builtin_amdgcn_permlane16_swap((unsigned)l, (unsigned)l, false, false); \
        const bool selA = __all(((((l & 16) ? (int)r[0] : (int)r[1])) == (l ^ 16)) ? 1 : 0); \
        use_r016 = selA ? ((l & 16) != 0) : ((l & 16) == 0); \
    }
#define CROSS16(p, out) { \
    const uint2v r_ = __builtin_amdgcn_permlane16_swap( \
        __float_as_uint(p), __float_as_uint(p), false, false); \
    out = __uint_as_float(use_r016 ? r_[0] : r_[1]); }
#else
#define PROBE16
#define CROSS16(p, out) out = __int_as_float(__builtin_amdgcn_ds_swizzle( \
        __float_as_int(p), 0x401F));
#endif

// ---- emission loads: round-13/16-PROVEN form (voff VGPR, uniform s-base) ---
#define ISS1(REG, TT, COL) {                                                \
    int ts_ = (TT);                                                         \
    ts_ = ts_ < 0 ? 0 : (ts_ > (Tn - 1) ? (Tn - 1) : ts_);                  \
    const unsigned voff_ = (unsigned)ts_ * (unsigned)(Ln * 4) + (COL);      \
    asm volatile("global_load_dword %0, %1, %2"                             \
                 : "=v"(REG) : "v"(voff_), "s"(xb)); }

#define ISSUE16(P, TB)                                                      \
    ISS1(P##0,  (TB),            col4O) ISS1(P##1,  (TB) + 1  * dtt, col4E) \
    ISS1(P##2,  (TB) + 2 * dtt,  col4O) ISS1(P##3,  (TB) + 3  * dtt, col4E) \
    ISS1(P##4,  (TB) + 4 * dtt,  col4O) ISS1(P##5,  (TB) + 5  * dtt, col4E) \
    ISS1(P##6,  (TB) + 6 * dtt,  col4O) ISS1(P##7,  (TB) + 7  * dtt, col4E) \
    ISS1(P##8,  (TB) + 8 * dtt,  col4O) ISS1(P##9,  (TB) + 9  * dtt, col4E) \
    ISS1(P##10, (TB) + 10 * dtt, col4O) ISS1(P##11, (TB) + 11 * dtt, col4E) \
    ISS1(P##12, (TB) + 12 * dtt, col4O) ISS1(P##13, (TB) + 13 * dtt, col4E) \
    ISS1(P##14, (TB) + 14 * dtt, col4O) ISS1(P##15, (TB) + 15 * dtt, col4E)

#define WAITALL(P)                                                          \
    asm volatile("s_waitcnt vmcnt(0)"                                       \
        : "+v"(P##0), "+v"(P##1), "+v"(P##2),  "+v"(P##3),                  \
          "+v"(P##4), "+v"(P##5), "+v"(P##6),  "+v"(P##7),                  \
          "+v"(P##8), "+v"(P##9), "+v"(P##10), "+v"(P##11),                 \
          "+v"(P##12), "+v"(P##13), "+v"(P##14), "+v"(P##15)                \
        : : "memory");

#define COPY16(D, S)                                                        \
    D##0 = S##0;   D##1 = S##1;   D##2 = S##2;   D##3 = S##3;               \
    D##4 = S##4;   D##5 = S##5;   D##6 = S##6;   D##7 = S##7;               \
    D##8 = S##8;   D##9 = S##9;   D##10 = S##10; D##11 = S##11;             \
    D##12 = S##12; D##13 = S##13; D##14 = S##14; D##15 = S##15;

// ---- fused rotate-multiply: VOP2 DPP (one instruction per term) ------------
#define MULDPP(ACC, XS, EV, T)                                              \
    asm("v_mul_f32_dpp %0, %1, %2 row_ror:" #T " row_mask:0xf bank_mask:0xf"\
        : "=v"(ACC) : "v"(XS), "v"(EV));

// ---- step core: TREE reduction (16 parallel DPP-muls -> 4-level add tree) --
// Replaces the depth-4 DPP-FMA chains: only ONE DPP hop on the critical path.
#define STEP_BODY(ET, CRX, PRE, NXTV)                                       \
    const float gcur = ggc;                                                 \
    if (PRE) ggc = __builtin_amdgcn_exp2f((NXTV) * LOG2E_F);                \
    float xs;                                                               \
    if constexpr (DIR) {                                                    \
        asm("v_mul_f32 %0, %1, %2\n\ts_nop 1"                               \
            : "=v"(xs) : "v"(x), "v"(gcur));                                \
    } else {                                                                \
        asm("v_mov_b32 %0, %1\n\ts_nop 1" : "=v"(xs) : "v"(x));             \
    }                                                                       \
    const float p0 = xs * ET[0];                                            \
    float p1, p2, p3, p4, p5, p6, p7;                                       \
    float p8, p9, p10, p11, p12, p13, p14, p15;                             \
    MULDPP(p1,  xs, ET[1],  1)   MULDPP(p2,  xs, ET[2],  2)                 \
    MULDPP(p3,  xs, ET[3],  3)   MULDPP(p4,  xs, ET[4],  4)                 \
    MULDPP(p5,  xs, ET[5],  5)   MULDPP(p6,  xs, ET[6],  6)                 \
    MULDPP(p7,  xs, ET[7],  7)   MULDPP(p8,  xs, ET[8],  8)                 \
    MULDPP(p9,  xs, ET[9],  9)   MULDPP(p10, xs, ET[10], 10)                \
    MULDPP(p11, xs, ET[11], 11)  MULDPP(p12, xs, ET[12], 12)                \
    MULDPP(p13, xs, ET[13], 13)  MULDPP(p14, xs, ET[14], 14)                \
    MULDPP(p15, xs, ET[15], 15)                                             \
    const float q0 = p0 + p1;    const float q1 = p2 + p3;                  \
    const float q2 = p4 + p5;    const float q3 = p6 + p7;                  \
    const float q4 = p8 + p9;    const float q5 = p10 + p11;                \
    const float q6 = p12 + p13;  const float q7 = p14 + p15;                \
    const float r0 = q0 + q1;    const float r1 = q2 + q3;                  \
    const float r2 = q4 + q5;    const float r3 = q6 + q7;                  \
    const float s0 = r0 + r1;    const float s1 = r2 + r3;                  \
    const float partial = s0 + s1;                                          \
    float cross; CRX(partial, cross)                                        \
    float full = partial + cross;                                           \
    if constexpr (!DIR) full *= gcur;      /* fw: emission at reader */

#define RENORM {                                                            \
    const int cb = __builtin_amdgcn_readfirstlane(                          \
        __float_as_int(fmaxf(capv, 1e-30f)));                               \
    const int ee = ((cb >> 23) & 255) - 127;                                \
    x *= __int_as_float((127 - ee) << 23);                                  \
    Mr += (float)ee; }

#define STEPF(ET, CRX, PRE, NXTV, CAP, RN) {                                \
    STEP_BODY(ET, CRX, PRE, NXTV)                                           \
    x = full;                                                               \
    if (CAP) capv = x;                                                      \
    if (RN) RENORM }

#define STEPT(R, ET, CRX, PRE, NXTV, CAP, RN) {                             \
    STEP_BODY(ET, CRX, PRE, NXTV)                                           \
    const bool act = ((kb + (R)) <= K);                                     \
    x = act ? full : x;                                                     \
    if (CAP) capv = x;                                                      \
    if (RN) RENORM }

#define STEPS16F(P)                                                         \
    ggc = __builtin_amdgcn_exp2f(P##0 * LOG2E_F);                           \
    STEPF(EiA, CROSS16, 1, P##1,  0, 0)                                     \
    STEPF(EiB, CROSS32, 1, P##2,  0, 0)                                     \
    STEPF(EiA, CROSS16, 1, P##3,  1, 0)                                     \
    STEPF(EiB, CROSS32, 1, P##4,  0, 1)                                     \
    STEPF(EiA, CROSS16, 1, P##5,  0, 0)                                     \
    STEPF(EiB, CROSS32, 1, P##6,  0, 0)                                     \
    STEPF(EiA, CROSS16, 1, P##7,  1, 0)                                     \
    STEPF(EiB, CROSS32, 1, P##8,  0, 1)                                     \
    STEPF(EiA, CROSS16, 1, P##9,  0, 0)                                     \
    STEPF(EiB, CROSS32, 1, P##10, 0, 0)                                     \
    STEPF(EiA, CROSS16, 1, P##11, 1, 0)                                     \
    STEPF(EiB, CROSS32, 1, P##12, 0, 1)                                     \
    STEPF(EiA, CROSS16, 1, P##13, 0, 0)                                     \
    STEPF(EiB, CROSS32, 1, P##14, 0, 0)                                     \
    STEPF(EiA, CROSS16, 1, P##15, 1, 0)                                     \
    STEPF(EiB, CROSS32, 0, P##15, 0, 1)                                     \
    kb += 16;

#define STEPS16T(P)                                                         \
    ggc = __builtin_amdgcn_exp2f(P##0 * LOG2E_F);                           \
    STEPT(0,  EiA, CROSS16, 1, P##1,  0, 0)                                 \
    STEPT(1,  EiB, CROSS32, 1, P##2,  0, 0)                                 \
    STEPT(2,  EiA, CROSS16, 1, P##3,  1, 0)                                 \
    STEPT(3,  EiB, CROSS32, 1, P##4,  0, 1)                                 \
    STEPT(4,  EiA, CROSS16, 1, P##5,  0, 0)                                 \
    STEPT(5,  EiB, CROSS32, 1, P##6,  0, 0)                                 \
    STEPT(6,  EiA, CROSS16, 1, P##7,  1, 0)                                 \
    STEPT(7,  EiB, CROSS32, 1, P##8,  0, 1)                                 \
    STEPT(8,  EiA, CROSS16, 1, P##9,  0, 0)                                 \
    STEPT(9,  EiB, CROSS32, 1, P##10, 0, 0)                                 \
    STEPT(10, EiA, CROSS16, 1, P##11, 1, 0)                                 \
    STEPT(11, EiB, CROSS32, 1, P##12, 0, 1)                                 \
    STEPT(12, EiA, CROSS16, 1, P##13, 0, 0)                                 \
    STEPT(13, EiB, CROSS32, 1, P##14, 0, 0)                                 \
    STEPT(14, EiA, CROSS16, 1, P##15, 1, 0)                                 \
    STEPT(15, EiB, CROSS32, 0, P##15, 0, 1)                                 \
    kb += 16;

#define EI_SETUP2                                                           \
    float EiA[16], EiB[16];                                                 \
    {                                                                       \
        float tmax = -3.4e38f;                                              \
        _Pragma("unroll")                                                   \
        for (int t = 0; t < 16; ++t) {                                      \
            const int sg = ror_minus ? ((k15 - t) & 15) : ((k15 + t) & 15); \
            const int iA = 16 * ihA + sg;                                   \
            const int iB = 16 * ihB + sg;                                   \
            const float tvA = DIR ? trans[labA * Ln + iA]                   \
                                  : trans[iA * Ln + labA];                  \
            const float tvB = DIR ? trans[labB * Ln + iB]                   \
                                  : trans[iB * Ln + labB];                  \
            EiA[t] = tvA;  EiB[t] = tvB;                                    \
            tmax = fmaxf(tmax, tvA);    /* EA spans all of trans */         \
        }                                                                   \
        _Pragma("unroll")                                                   \
        for (int off = 1; off < 64; off <<= 1)                              \
            tmax = fmaxf(tmax, __shfl_xor(tmax, off));                      \
        tmax2 = tmax * LOG2E_F;                                             \
        _Pragma("unroll")                                                   \
        for (int t = 0; t < 16; ++t) {                                      \
            EiA[t] = __builtin_amdgcn_exp2f((EiA[t] - tmax) * LOG2E_F);     \
            EiB[t] = __builtin_amdgcn_exp2f((EiB[t] - tmax) * LOG2E_F);     \
        }                                                                   \
    }

// ---- chain body, DIR compile-time ------------------------------------------
template<int DIR>
__device__ __forceinline__ void chain_run(const float* __restrict__ logits,
                                          const float* __restrict__ trans,
                                          const int b, const int l,
                                          const int len,
                                          float* __restrict__ ws)
{
    const int k15 = l & 15;
    const int labB = l & 31;                        // phi label
    const int labA = (l & 15) | ((l >> 5) << 4);    // sigma label
    const int ihA  = (l >> 4) & 1;                  // row-half, phi-layout
    const int ihB  = (l >> 5) & 1;                  // row-half, sigma-layout

    const int m  = (len + 1) >> 1;
    const int K  = DIR ? (len - m) : (m - 1);
    const int nfull = K >> 4;
    const int ktail = K & 15;

    const float* xb = logits + (size_t)b * (Tn * Ln);

    const int w0 = __builtin_amdgcn_readfirstlane(
        __builtin_amdgcn_update_dpp(0, l, 0x121, 0xF, 0xF, true));
    const bool ror_minus = (w0 == 15);
    PROBE32
    PROBE16

    float tmax2;
    EI_SETUP2

    // init state in phi-layout
    float x, Minit;
    if constexpr (DIR == 0) {
        const float a0v = xb[labB] * LOG2E_F;
        float mx = a0v;
        #pragma unroll
        for (int off = 1; off < 64; off <<= 1)
            mx = fmaxf(mx, __shfl_xor(mx, off));
        x = __builtin_amdgcn_exp2f(a0v - mx);
        Minit = mx;
    } else {
        x = 1.0f;
        Minit = 0.0f;
    }
    float Mr = 0.0f;
    float capv = x;

    const unsigned col4O = (unsigned)(DIR ? labB : labA) * 4u;
    const unsigned col4E = (unsigned)(DIR ? labA : labB) * 4u;
    const int dtt = DIR ? -1 : 1;
    const int t0  = DIR ? (len - 1) : 1;

    float A0, A1, A2, A3, A4, A5, A6, A7;
    float A8, A9, A10, A11, A12, A13, A14, A15;
    float B0, B1, B2, B3, B4, B5, B6, B7;
    float B8, B9, B10, B11, B12, B13, B14, B15;

    float ggc = 1.0f;
    int kb = 1;

    ISSUE16(B, t0)
    WAITALL(B)
    COPY16(A, B)
    int tnext = t0 + 16 * dtt;

    for (int g = 0; g < nfull; ++g) {
        ISSUE16(B, tnext)
        tnext += 16 * dtt;
        __builtin_amdgcn_sched_barrier(0);
        STEPS16F(A)
        __builtin_amdgcn_sched_barrier(0);
        WAITALL(B)
        __builtin_amdgcn_sched_barrier(0);
        COPY16(A, B)
    }
    if (ktail) {
        STEPS16T(A)
    }

    asm volatile("s_waitcnt vmcnt(0)" ::: "memory");

    const float M = Minit + (float)K * tmax2 + Mr;

    // final layout depends on parity of K: even -> phi, odd -> sigma
    float* wsrow = ws + (size_t)(b * 2 + DIR) * 33;
    if (K & 1) {
        if ((l & 16) == 0) wsrow[labA] = x;
    } else {
        if (l < 32) wsrow[l] = x;
    }
    if (l == 0) wsrow[32] = M;
}

__global__ __launch_bounds__(64)
void crf_chain_kernel(const float* __restrict__ logits,
                      const float* __restrict__ trans,
                      const int* __restrict__ seq_lens,
                      float* __restrict__ ws)
{
    const int blk = blockIdx.x;
    const int b   = blk >> 1;
    const int dir = blk & 1;
    const int l   = threadIdx.x;

    int len = seq_lens[b];
    len = len < 1 ? 1 : (len > Tn ? Tn : len);
    len = __builtin_amdgcn_readfirstlane(len);   // uniform: scalar t-arithmetic

    if (dir == 0) chain_run<0>(logits, trans, b, l, len, ws);
    else          chain_run<1>(logits, trans, b, l, len, ws);
}

// ---- DPP RAW-latency probe (output-inert; ws overwritten by chain) ---------
// Serial chain of v_mul_f32_dpp: each op's rotated src0 is the previous
// result. dur / NIT = dependent DPP latency (incl. any HW stall / wait
// states). Multiplier ~1.0 keeps values bounded.
template<int NIT>
__global__ __launch_bounds__(64)
void crf_probe_dpp(float* __restrict__ ws)
{
    const int l = threadIdx.x;
    float x = 1.0f + (float)l * 0.001f;
    const float c = 0.99999988f;
    for (int i = 0; i < NIT / 16; ++i) {
        #pragma unroll
        for (int r = 0; r < 16; ++r) {
            float y;
            asm("v_mul_f32_dpp %0, %1, %2 row_ror:1 row_mask:0xf bank_mask:0xf"
                : "=v"(y) : "v"(x), "v"(c));
            x = y;
        }
    }
    if (l == 0) ws[(size_t)blockIdx.x * 33] = x;
}

// ---- combine kernel: 256 threads (gather latency spread over 4 waves) ------
__global__ __launch_bounds__(256)
void crf_combine_kernel(const float* __restrict__ logits,
                        const float* __restrict__ trans,
                        const int* __restrict__ labels,
                        const int* __restrict__ seq_lens,
                        const float* __restrict__ ws,
                        float* __restrict__ out)
{
    const int b   = blockIdx.x;
    const int tid = threadIdx.x;

    int len = seq_lens[b];
    len = len < 1 ? 1 : (len > Tn ? Tn : len);

    const int*   lb = labels + (size_t)b * Tn;
    const float* xb = logits + (size_t)b * (Tn * Ln);

    float acc = 0.f;
    for (int t = tid; t < len; t += 256) {
        const int lt = lb[t];
        acc += xb[t * Ln + lt];
        if (t >= 1) acc += trans[lb[t - 1] * Ln + lt];
    }
    #pragma unroll
    for (int off = 1; off < 64; off <<= 1)
        acc += __shfl_xor(acc, off);

    __shared__ float wred[4];
    if ((tid & 63) == 0) wred[tid >> 6] = acc;
    __syncthreads();

    if (tid < 64) {
        const float gold = (wred[0] + wred[1]) + (wred[2] + wred[3]);
        const int j = tid & 31;
        const float* wf = ws + (size_t)(b * 2 + 0) * 33;
        const float* wb = ws + (size_t)(b * 2 + 1) * 33;
        float term = wf[j] * wb[j];
        #pragma unroll
        for (int off = 1; off < 32; off <<= 1)
            term += __shfl_xor(term, off);
        if (tid == 0) {
            const float Mf = wf[32], Mb = wb[32];
            out[b] = gold - (Mf + Mb + __builtin_amdgcn_logf(term)) * LN2_F;
        }
    }
}

extern "C" void kernel_launch(void* const* d_in, const int* in_sizes, int n_in,
                              void* d_out, int out_size, void* d_ws, size_t ws_size,
                              hipStream_t stream) {
    const float* logits   = (const float*)d_in[0];
    const float* trans    = (const float*)d_in[1];
    const int*   labels   = (const int*)d_in[2];
    const int*   seq_lens = (const int*)d_in[3];
    float* out = (float*)d_out;
    float* ws  = (float*)d_ws;    // 2048 * 33 floats = 270 KB

    // latency probe first (speed datum only; ws overwritten by chain kernel)
    crf_probe_dpp<12288><<<Bn * 2, 64, 0, stream>>>(ws);

    crf_chain_kernel<<<Bn * 2, 64, 0, stream>>>(logits, trans, seq_lens, ws);
    crf_combine_kernel<<<Bn, 256, 0, stream>>>(logits, trans, labels, seq_lens, ws, out);
}

// Round 23
// 94.266 us; speedup vs baseline: 1.0555x; 1.0555x over previous
//
#include <hip/hip_runtime.h>
#include <math.h>

#define LOG2E_F 1.4426950408889634f
#define LN2_F   0.6931471805599453f

constexpr int Bn = 1024;
constexpr int Tn = 512;
constexpr int Ln = 32;

typedef unsigned int uint2v __attribute__((ext_vector_type(2)));

// ---- cross-lane swap mapping probes (hardware truth, computed once) --------
__device__ __forceinline__ bool probe32sel(int l) {
#if __has_builtin(__builtin_amdgcn_permlane32_swap)
    const uint2v r = __builtin_amdgcn_permlane32_swap((unsigned)l, (unsigned)l, false, false);
    const bool selA = __all((((l < 32) ? (int)r[1] : (int)r[0]) == (l ^ 32)) ? 1 : 0);
    return selA ? (l < 32) : (l >= 32);
#else
    return false;
#endif
}
__device__ __forceinline__ bool probe16sel(int l) {
#if __has_builtin(__builtin_amdgcn_permlane16_swap)
    const uint2v r = __builtin_amdgcn_permlane16_swap((unsigned)l, (unsigned)l, false, false);
    const bool selA = __all(((((l & 16) ? (int)r[0] : (int)r[1])) == (l ^ 16)) ? 1 : 0);
    return selA ? ((l & 16) != 0) : ((l & 16) == 0);
#else
    return false;
#endif
}

// ---- cross-lane xor-swap: PL=true -> permlane (VALU), PL=false -> DS pipe --
template<bool PL, int SEL>
__device__ __forceinline__ float crossx(float p, bool uy, bool ur) {
    if constexpr (SEL == 32) {
#if __has_builtin(__builtin_amdgcn_permlane32_swap)
        if constexpr (PL) {
            const uint2v r = __builtin_amdgcn_permlane32_swap(
                __float_as_uint(p), __float_as_uint(p), false, false);
            return __uint_as_float(uy ? r[1] : r[0]);
        }
#endif
        return __shfl_xor(p, 32);
    } else {
#if __has_builtin(__builtin_amdgcn_permlane16_swap)
        if constexpr (PL) {
            const uint2v r = __builtin_amdgcn_permlane16_swap(
                __float_as_uint(p), __float_as_uint(p), false, false);
            return __uint_as_float(ur ? r[0] : r[1]);
        }
#endif
        return __int_as_float(__builtin_amdgcn_ds_swizzle(
            __float_as_int(p), 0x401F));   // BitMode xor=16, and=0x1F
    }
}

// ---- emission loads: round-13/16-PROVEN form (voff VGPR, uniform s-base) ---
#define ISS1(REG, TT, COL) {                                                \
    int ts_ = (TT);                                                         \
    ts_ = ts_ < 0 ? 0 : (ts_ > (Tn - 1) ? (Tn - 1) : ts_);                  \
    const unsigned voff_ = (unsigned)ts_ * (unsigned)(Ln * 4) + (COL);      \
    asm volatile("global_load_dword %0, %1, %2"                             \
                 : "=v"(REG) : "v"(voff_), "s"(xb)); }

#define ISSUE16(P, TB)                                                      \
    ISS1(P##0,  (TB),            col4O) ISS1(P##1,  (TB) + 1  * dtt, col4E) \
    ISS1(P##2,  (TB) + 2 * dtt,  col4O) ISS1(P##3,  (TB) + 3  * dtt, col4E) \
    ISS1(P##4,  (TB) + 4 * dtt,  col4O) ISS1(P##5,  (TB) + 5  * dtt, col4E) \
    ISS1(P##6,  (TB) + 6 * dtt,  col4O) ISS1(P##7,  (TB) + 7  * dtt, col4E) \
    ISS1(P##8,  (TB) + 8 * dtt,  col4O) ISS1(P##9,  (TB) + 9  * dtt, col4E) \
    ISS1(P##10, (TB) + 10 * dtt, col4O) ISS1(P##11, (TB) + 11 * dtt, col4E) \
    ISS1(P##12, (TB) + 12 * dtt, col4O) ISS1(P##13, (TB) + 13 * dtt, col4E) \
    ISS1(P##14, (TB) + 14 * dtt, col4O) ISS1(P##15, (TB) + 15 * dtt, col4E)

#define WAITALL(P)                                                          \
    asm volatile("s_waitcnt vmcnt(0)"                                       \
        : "+v"(P##0), "+v"(P##1), "+v"(P##2),  "+v"(P##3),                  \
          "+v"(P##4), "+v"(P##5), "+v"(P##6),  "+v"(P##7),                  \
          "+v"(P##8), "+v"(P##9), "+v"(P##10), "+v"(P##11),                 \
          "+v"(P##12), "+v"(P##13), "+v"(P##14), "+v"(P##15)                \
        : : "memory");

#define COPY16(D, S)                                                        \
    D##0 = S##0;   D##1 = S##1;   D##2 = S##2;   D##3 = S##3;               \
    D##4 = S##4;   D##5 = S##5;   D##6 = S##6;   D##7 = S##7;               \
    D##8 = S##8;   D##9 = S##9;   D##10 = S##10; D##11 = S##11;             \
    D##12 = S##12; D##13 = S##13; D##14 = S##14; D##15 = S##15;

// ---- fused rotate-multiply: VOP2 DPP (one instruction per term) ------------
#define MULDPP(ACC, XS, EV, T)                                              \
    asm("v_mul_f32_dpp %0, %1, %2 row_ror:" #T " row_mask:0xf bank_mask:0xf"\
        : "=v"(ACC) : "v"(XS), "v"(EV));

// ---- step core: TREE reduction (verified round 22, absmax 0.0) -------------
#define STEP_BODY(ET, SEL, PRE, NXTV)                                       \
    const float gcur = ggc;                                                 \
    if (PRE) ggc = __builtin_amdgcn_exp2f((NXTV) * LOG2E_F);                \
    float xs;                                                               \
    if constexpr (DIR) {                                                    \
        asm("v_mul_f32 %0, %1, %2\n\ts_nop 1"                               \
            : "=v"(xs) : "v"(x), "v"(gcur));                                \
    } else {                                                                \
        asm("v_mov_b32 %0, %1\n\ts_nop 1" : "=v"(xs) : "v"(x));             \
    }                                                                       \
    const float p0 = xs * ET[0];                                            \
    float p1, p2, p3, p4, p5, p6, p7;                                       \
    float p8, p9, p10, p11, p12, p13, p14, p15;                             \
    MULDPP(p1,  xs, ET[1],  1)   MULDPP(p2,  xs, ET[2],  2)                 \
    MULDPP(p3,  xs, ET[3],  3)   MULDPP(p4,  xs, ET[4],  4)                 \
    MULDPP(p5,  xs, ET[5],  5)   MULDPP(p6,  xs, ET[6],  6)                 \
    MULDPP(p7,  xs, ET[7],  7)   MULDPP(p8,  xs, ET[8],  8)                 \
    MULDPP(p9,  xs, ET[9],  9)   MULDPP(p10, xs, ET[10], 10)                \
    MULDPP(p11, xs, ET[11], 11)  MULDPP(p12, xs, ET[12], 12)                \
    MULDPP(p13, xs, ET[13], 13)  MULDPP(p14, xs, ET[14], 14)                \
    MULDPP(p15, xs, ET[15], 15)                                             \
    const float q0 = p0 + p1;    const float q1 = p2 + p3;                  \
    const float q2 = p4 + p5;    const float q3 = p6 + p7;                  \
    const float q4 = p8 + p9;    const float q5 = p10 + p11;                \
    const float q6 = p12 + p13;  const float q7 = p14 + p15;                \
    const float r0 = q0 + q1;    const float r1 = q2 + q3;                  \
    const float r2 = q4 + q5;    const float r3 = q6 + q7;                  \
    const float s0 = r0 + r1;    const float s1 = r2 + r3;                  \
    const float partial = s0 + s1;                                          \
    const float cross = crossx<PL, SEL>(partial, uy32, ur16);               \
    float full = partial + cross;                                           \
    if constexpr (!DIR) full *= gcur;      /* fw: emission at reader */

#define RENORM {                                                            \
    const int cb = __builtin_amdgcn_readfirstlane(                          \
        __float_as_int(fmaxf(capv, 1e-30f)));                               \
    const int ee = ((cb >> 23) & 255) - 127;                                \
    x *= __int_as_float((127 - ee) << 23);                                  \
    Mr += (float)ee; }

#define STEPF(ET, SEL, PRE, NXTV, CAP, RN) {                                \
    STEP_BODY(ET, SEL, PRE, NXTV)                                           \
    x = full;                                                               \
    if (CAP) capv = x;                                                      \
    if (RN) RENORM }

#define STEPT(R, ET, SEL, PRE, NXTV, CAP, RN) {                             \
    STEP_BODY(ET, SEL, PRE, NXTV)                                           \
    const bool act = ((kb + (R)) <= K);                                     \
    x = act ? full : x;                                                     \
    if (CAP) capv = x;                                                      \
    if (RN) RENORM }

#define STEPS16F(P)                                                         \
    ggc = __builtin_amdgcn_exp2f(P##0 * LOG2E_F);                           \
    STEPF(EiA, 16, 1, P##1,  0, 0)                                          \
    STEPF(EiB, 32, 1, P##2,  0, 0)                                          \
    STEPF(EiA, 16, 1, P##3,  1, 0)                                          \
    STEPF(EiB, 32, 1, P##4,  0, 1)                                          \
    STEPF(EiA, 16, 1, P##5,  0, 0)                                          \
    STEPF(EiB, 32, 1, P##6,  0, 0)                                          \
    STEPF(EiA, 16, 1, P##7,  1, 0)                                          \
    STEPF(EiB, 32, 1, P##8,  0, 1)                                          \
    STEPF(EiA, 16, 1, P##9,  0, 0)                                          \
    STEPF(EiB, 32, 1, P##10, 0, 0)                                          \
    STEPF(EiA, 16, 1, P##11, 1, 0)                                          \
    STEPF(EiB, 32, 1, P##12, 0, 1)                                          \
    STEPF(EiA, 16, 1, P##13, 0, 0)                                          \
    STEPF(EiB, 32, 1, P##14, 0, 0)                                          \
    STEPF(EiA, 16, 1, P##15, 1, 0)                                          \
    STEPF(EiB, 32, 0, P##15, 0, 1)                                          \
    kb += 16;

#define STEPS16T(P)                                                         \
    ggc = __builtin_amdgcn_exp2f(P##0 * LOG2E_F);                           \
    STEPT(0,  EiA, 16, 1, P##1,  0, 0)                                      \
    STEPT(1,  EiB, 32, 1, P##2,  0, 0)                                      \
    STEPT(2,  EiA, 16, 1, P##3,  1, 0)                                      \
    STEPT(3,  EiB, 32, 1, P##4,  0, 1)                                      \
    STEPT(4,  EiA, 16, 1, P##5,  0, 0)                                      \
    STEPT(5,  EiB, 32, 1, P##6,  0, 0)                                      \
    STEPT(6,  EiA, 16, 1, P##7,  1, 0)                                      \
    STEPT(7,  EiB, 32, 1, P##8,  0, 1)                                      \
    STEPT(8,  EiA, 16, 1, P##9,  0, 0)                                      \
    STEPT(9,  EiB, 32, 1, P##10, 0, 0)                                      \
    STEPT(10, EiA, 16, 1, P##11, 1, 0)                                      \
    STEPT(11, EiB, 32, 1, P##12, 0, 1)                                      \
    STEPT(12, EiA, 16, 1, P##13, 0, 0)                                      \
    STEPT(13, EiB, 32, 1, P##14, 0, 0)                                      \
    STEPT(14, EiA, 16, 1, P##15, 1, 0)                                      \
    STEPT(15, EiB, 32, 0, P##15, 0, 1)                                      \
    kb += 16;

#define EI_SETUP2                                                           \
    float EiA[16], EiB[16];                                                 \
    {                                                                       \
        float tmax = -3.4e38f;                                              \
        _Pragma("unroll")                                                   \
        for (int t = 0; t < 16; ++t) {                                      \
            const int sg = ror_minus ? ((k15 - t) & 15) : ((k15 + t) & 15); \
            const int iA = 16 * ihA + sg;                                   \
            const int iB = 16 * ihB + sg;                                   \
            const float tvA = DIR ? trans[labA * Ln + iA]                   \
                                  : trans[iA * Ln + labA];                  \
            const float tvB = DIR ? trans[labB * Ln + iB]                   \
                                  : trans[iB * Ln + labB];                  \
            EiA[t] = tvA;  EiB[t] = tvB;                                    \
            tmax = fmaxf(tmax, tvA);    /* EA spans all of trans */         \
        }                                                                   \
        _Pragma("unroll")                                                   \
        for (int off = 1; off < 64; off <<= 1)                              \
            tmax = fmaxf(tmax, __shfl_xor(tmax, off));                      \
        tmax2 = tmax * LOG2E_F;                                             \
        _Pragma("unroll")                                                   \
        for (int t = 0; t < 16; ++t) {                                      \
            EiA[t] = __builtin_amdgcn_exp2f((EiA[t] - tmax) * LOG2E_F);     \
            EiB[t] = __builtin_amdgcn_exp2f((EiB[t] - tmax) * LOG2E_F);     \
        }                                                                   \
    }

// ---- chain body, DIR + cross-implementation compile-time -------------------
template<int DIR, bool PL>
__device__ __forceinline__ void chain_run(const float* __restrict__ logits,
                                          const float* __restrict__ trans,
                                          const int b, const int l,
                                          const int len,
                                          float* __restrict__ ws)
{
    const int k15 = l & 15;
    const int labB = l & 31;                        // phi label
    const int labA = (l & 15) | ((l >> 5) << 4);    // sigma label
    const int ihA  = (l >> 4) & 1;                  // row-half, phi-layout
    const int ihB  = (l >> 5) & 1;                  // row-half, sigma-layout

    const int m  = (len + 1) >> 1;
    const int K  = DIR ? (len - m) : (m - 1);
    const int nfull = K >> 4;
    const int ktail = K & 15;

    const float* xb = logits + (size_t)b * (Tn * Ln);

    const int w0 = __builtin_amdgcn_readfirstlane(
        __builtin_amdgcn_update_dpp(0, l, 0x121, 0xF, 0xF, true));
    const bool ror_minus = (w0 == 15);
    const bool uy32 = probe32sel(l);
    const bool ur16 = probe16sel(l);

    float tmax2;
    EI_SETUP2

    // init state in phi-layout
    float x, Minit;
    if constexpr (DIR == 0) {
        const float a0v = xb[labB] * LOG2E_F;
        float mx = a0v;
        #pragma unroll
        for (int off = 1; off < 64; off <<= 1)
            mx = fmaxf(mx, __shfl_xor(mx, off));
        x = __builtin_amdgcn_exp2f(a0v - mx);
        Minit = mx;
    } else {
        x = 1.0f;
        Minit = 0.0f;
    }
    float Mr = 0.0f;
    float capv = x;

    const unsigned col4O = (unsigned)(DIR ? labB : labA) * 4u;
    const unsigned col4E = (unsigned)(DIR ? labA : labB) * 4u;
    const int dtt = DIR ? -1 : 1;
    const int t0  = DIR ? (len - 1) : 1;

    float A0, A1, A2, A3, A4, A5, A6, A7;
    float A8, A9, A10, A11, A12, A13, A14, A15;
    float B0, B1, B2, B3, B4, B5, B6, B7;
    float B8, B9, B10, B11, B12, B13, B14, B15;

    float ggc = 1.0f;
    int kb = 1;

    ISSUE16(B, t0)
    WAITALL(B)
    COPY16(A, B)
    int tnext = t0 + 16 * dtt;

    for (int g = 0; g < nfull; ++g) {
        ISSUE16(B, tnext)
        tnext += 16 * dtt;
        __builtin_amdgcn_sched_barrier(0);
        STEPS16F(A)
        __builtin_amdgcn_sched_barrier(0);
        WAITALL(B)
        __builtin_amdgcn_sched_barrier(0);
        COPY16(A, B)
    }
    if (ktail) {
        STEPS16T(A)
    }

    asm volatile("s_waitcnt vmcnt(0)" ::: "memory");

    const float M = Minit + (float)K * tmax2 + Mr;

    // final layout depends on parity of K: even -> phi, odd -> sigma
    float* wsrow = ws + (size_t)(b * 2 + DIR) * 33;
    if (K & 1) {
        if ((l & 16) == 0) wsrow[labA] = x;
    } else {
        if (l < 32) wsrow[l] = x;
    }
    if (l == 0) wsrow[32] = M;
}

template<bool PL>
__global__ __launch_bounds__(64)
void crf_chain_kernel(const float* __restrict__ logits,
                      const float* __restrict__ trans,
                      const int* __restrict__ seq_lens,
                      float* __restrict__ ws)
{
    const int blk = blockIdx.x;
    const int b   = blk >> 1;
    const int dir = blk & 1;
    const int l   = threadIdx.x;

    int len = seq_lens[b];
    len = len < 1 ? 1 : (len > Tn ? Tn : len);
    len = __builtin_amdgcn_readfirstlane(len);   // uniform: scalar t-arithmetic

    if (dir == 0) chain_run<0, PL>(logits, trans, b, l, len, ws);
    else          chain_run<1, PL>(logits, trans, b, l, len, ws);
}

// ---- combine kernel: 256 threads (gather latency spread over 4 waves) ------
__global__ __launch_bounds__(256)
void crf_combine_kernel(const float* __restrict__ logits,
                        const float* __restrict__ trans,
                        const int* __restrict__ labels,
                        const int* __restrict__ seq_lens,
                        const float* __restrict__ ws,
                        float* __restrict__ out)
{
    const int b   = blockIdx.x;
    const int tid = threadIdx.x;

    int len = seq_lens[b];
    len = len < 1 ? 1 : (len > Tn ? Tn : len);

    const int*   lb = labels + (size_t)b * Tn;
    const float* xb = logits + (size_t)b * (Tn * Ln);

    float acc = 0.f;
    for (int t = tid; t < len; t += 256) {
        const int lt = lb[t];
        acc += xb[t * Ln + lt];
        if (t >= 1) acc += trans[lb[t - 1] * Ln + lt];
    }
    #pragma unroll
    for (int off = 1; off < 64; off <<= 1)
        acc += __shfl_xor(acc, off);

    __shared__ float wred[4];
    if ((tid & 63) == 0) wred[tid >> 6] = acc;
    __syncthreads();

    if (tid < 64) {
        const float gold = (wred[0] + wred[1]) + (wred[2] + wred[3]);
        const int j = tid & 31;
        const float* wf = ws + (size_t)(b * 2 + 0) * 33;
        const float* wb = ws + (size_t)(b * 2 + 1) * 33;
        float term = wf[j] * wb[j];
        #pragma unroll
        for (int off = 1; off < 32; off <<= 1)
            term += __shfl_xor(term, off);
        if (tid == 0) {
            const float Mf = wf[32], Mb = wb[32];
            out[b] = gold - (Mf + Mb + __builtin_amdgcn_logf(term)) * LN2_F;
        }
    }
}

extern "C" void kernel_launch(void* const* d_in, const int* in_sizes, int n_in,
                              void* d_out, int out_size, void* d_ws, size_t ws_size,
                              hipStream_t stream) {
    const float* logits   = (const float*)d_in[0];
    const float* trans    = (const float*)d_in[1];
    const int*   labels   = (const int*)d_in[2];
    const int*   seq_lens = (const int*)d_in[3];
    float* out = (float*)d_out;
    float* ws  = (float*)d_ws;    // 2048 * 33 floats = 270 KB

    // A/B: DS-pipe crosses first (timing datum), then permlane crosses
    // (recomputes bit-identical values into ws -> correctness unaffected).
    crf_chain_kernel<false><<<Bn * 2, 64, 0, stream>>>(logits, trans, seq_lens, ws);
    crf_chain_kernel<true ><<<Bn * 2, 64, 0, stream>>>(logits, trans, seq_lens, ws);
    crf_combine_kernel<<<Bn, 256, 0, stream>>>(logits, trans, labels, seq_lens, ws, out);
}

// Round 24
// 53.922 us; speedup vs baseline: 1.8453x; 1.7482x over previous
//
#include <hip/hip_runtime.h>
#include <math.h>

#define LOG2E_F 1.4426950408889634f
#define LN2_F   0.6931471805599453f

constexpr int Bn = 1024;
constexpr int Tn = 512;
constexpr int Ln = 32;

typedef unsigned int uint2v __attribute__((ext_vector_type(2)));

// ---- cross-lane swap mapping probes (hardware truth, computed once) --------
__device__ __forceinline__ bool probe32sel(int l) {
#if __has_builtin(__builtin_amdgcn_permlane32_swap)
    const uint2v r = __builtin_amdgcn_permlane32_swap((unsigned)l, (unsigned)l, false, false);
    const bool selA = __all((((l < 32) ? (int)r[1] : (int)r[0]) == (l ^ 32)) ? 1 : 0);
    return selA ? (l < 32) : (l >= 32);
#else
    return false;
#endif
}
__device__ __forceinline__ bool probe16sel(int l) {
#if __has_builtin(__builtin_amdgcn_permlane16_swap)
    const uint2v r = __builtin_amdgcn_permlane16_swap((unsigned)l, (unsigned)l, false, false);
    const bool selA = __all(((((l & 16) ? (int)r[0] : (int)r[1])) == (l ^ 16)) ? 1 : 0);
    return selA ? ((l & 16) != 0) : ((l & 16) == 0);
#else
    return false;
#endif
}

// ---- cross-lane xor-swap (permlane VALU ops; verified round 22/23) ---------
template<int SEL>
__device__ __forceinline__ float crossx(float p, bool uy, bool ur) {
    if constexpr (SEL == 32) {
#if __has_builtin(__builtin_amdgcn_permlane32_swap)
        const uint2v r = __builtin_amdgcn_permlane32_swap(
            __float_as_uint(p), __float_as_uint(p), false, false);
        return __uint_as_float(uy ? r[1] : r[0]);
#else
        return __shfl_xor(p, 32);
#endif
    } else {
#if __has_builtin(__builtin_amdgcn_permlane16_swap)
        const uint2v r = __builtin_amdgcn_permlane16_swap(
            __float_as_uint(p), __float_as_uint(p), false, false);
        return __uint_as_float(ur ? r[0] : r[1]);
#else
        return __int_as_float(__builtin_amdgcn_ds_swizzle(
            __float_as_int(p), 0x401F));   // BitMode xor=16, and=0x1F
#endif
    }
}

// ---- emission loads: round-13/16-PROVEN form (voff VGPR, uniform s-base) ---
#define ISS1(REG, TT, COL) {                                                \
    int ts_ = (TT);                                                         \
    ts_ = ts_ < 0 ? 0 : (ts_ > (Tn - 1) ? (Tn - 1) : ts_);                  \
    const unsigned voff_ = (unsigned)ts_ * (unsigned)(Ln * 4) + (COL);      \
    asm volatile("global_load_dword %0, %1, %2"                             \
                 : "=v"(REG) : "v"(voff_), "s"(xb)); }

#define ISSUE16(P, TB)                                                      \
    ISS1(P##0,  (TB),            col4O) ISS1(P##1,  (TB) + 1  * dtt, col4E) \
    ISS1(P##2,  (TB) + 2 * dtt,  col4O) ISS1(P##3,  (TB) + 3  * dtt, col4E) \
    ISS1(P##4,  (TB) + 4 * dtt,  col4O) ISS1(P##5,  (TB) + 5  * dtt, col4E) \
    ISS1(P##6,  (TB) + 6 * dtt,  col4O) ISS1(P##7,  (TB) + 7  * dtt, col4E) \
    ISS1(P##8,  (TB) + 8 * dtt,  col4O) ISS1(P##9,  (TB) + 9  * dtt, col4E) \
    ISS1(P##10, (TB) + 10 * dtt, col4O) ISS1(P##11, (TB) + 11 * dtt, col4E) \
    ISS1(P##12, (TB) + 12 * dtt, col4O) ISS1(P##13, (TB) + 13 * dtt, col4E) \
    ISS1(P##14, (TB) + 14 * dtt, col4O) ISS1(P##15, (TB) + 15 * dtt, col4E)

#define WAITALL(P)                                                          \
    asm volatile("s_waitcnt vmcnt(0)"                                       \
        : "+v"(P##0), "+v"(P##1), "+v"(P##2),  "+v"(P##3),                  \
          "+v"(P##4), "+v"(P##5), "+v"(P##6),  "+v"(P##7),                  \
          "+v"(P##8), "+v"(P##9), "+v"(P##10), "+v"(P##11),                 \
          "+v"(P##12), "+v"(P##13), "+v"(P##14), "+v"(P##15)                \
        : : "memory");

#define COPY16(D, S)                                                        \
    D##0 = S##0;   D##1 = S##1;   D##2 = S##2;   D##3 = S##3;               \
    D##4 = S##4;   D##5 = S##5;   D##6 = S##6;   D##7 = S##7;               \
    D##8 = S##8;   D##9 = S##9;   D##10 = S##10; D##11 = S##11;             \
    D##12 = S##12; D##13 = S##13; D##14 = S##14; D##15 = S##15;

// ---- fused rotate-multiply: VOP2 DPP (one instruction per term) ------------
#define MULDPP(ACC, XS, EV, T)                                              \
    asm("v_mul_f32_dpp %0, %1, %2 row_ror:" #T " row_mask:0xf bank_mask:0xf"\
        : "=v"(ACC) : "v"(XS), "v"(EV));

// ---- step core: TREE reduction (verified rounds 22/23, absmax 0.0) ---------
#define STEP_BODY(ET, SEL, PRE, NXTV)                                       \
    const float gcur = ggc;                                                 \
    if (PRE) ggc = __builtin_amdgcn_exp2f((NXTV) * LOG2E_F);                \
    float xs;                                                               \
    if constexpr (DIR) {                                                    \
        asm("v_mul_f32 %0, %1, %2\n\ts_nop 1"                               \
            : "=v"(xs) : "v"(x), "v"(gcur));                                \
    } else {                                                                \
        asm("v_mov_b32 %0, %1\n\ts_nop 1" : "=v"(xs) : "v"(x));             \
    }                                                                       \
    const float p0 = xs * ET[0];                                            \
    float p1, p2, p3, p4, p5, p6, p7;                                       \
    float p8, p9, p10, p11, p12, p13, p14, p15;                             \
    MULDPP(p1,  xs, ET[1],  1)   MULDPP(p2,  xs, ET[2],  2)                 \
    MULDPP(p3,  xs, ET[3],  3)   MULDPP(p4,  xs, ET[4],  4)                 \
    MULDPP(p5,  xs, ET[5],  5)   MULDPP(p6,  xs, ET[6],  6)                 \
    MULDPP(p7,  xs, ET[7],  7)   MULDPP(p8,  xs, ET[8],  8)                 \
    MULDPP(p9,  xs, ET[9],  9)   MULDPP(p10, xs, ET[10], 10)                \
    MULDPP(p11, xs, ET[11], 11)  MULDPP(p12, xs, ET[12], 12)                \
    MULDPP(p13, xs, ET[13], 13)  MULDPP(p14, xs, ET[14], 14)                \
    MULDPP(p15, xs, ET[15], 15)                                             \
    const float q0 = p0 + p1;    const float q1 = p2 + p3;                  \
    const float q2 = p4 + p5;    const float q3 = p6 + p7;                  \
    const float q4 = p8 + p9;    const float q5 = p10 + p11;                \
    const float q6 = p12 + p13;  const float q7 = p14 + p15;                \
    const float r0 = q0 + q1;    const float r1 = q2 + q3;                  \
    const float r2 = q4 + q5;    const float r3 = q6 + q7;                  \
    const float s0 = r0 + r1;    const float s1 = r2 + r3;                  \
    const float partial = s0 + s1;                                          \
    const float cross = crossx<SEL>(partial, uy32, ur16);                   \
    float full = partial + cross;                                           \
    if constexpr (!DIR) full *= gcur;      /* fw: emission at reader */

#define RENORM {                                                            \
    const int cb = __builtin_amdgcn_readfirstlane(                          \
        __float_as_int(fmaxf(capv, 1e-30f)));                               \
    const int ee = ((cb >> 23) & 255) - 127;                                \
    x *= __int_as_float((127 - ee) << 23);                                  \
    Mr += (float)ee; }

#define STEPF(ET, SEL, PRE, NXTV, CAP, RN) {                                \
    STEP_BODY(ET, SEL, PRE, NXTV)                                           \
    x = full;                                                               \
    if (CAP) capv = x;                                                      \
    if (RN) RENORM }

#define STEPT(R, ET, SEL, PRE, NXTV, CAP, RN) {                             \
    STEP_BODY(ET, SEL, PRE, NXTV)                                           \
    const bool act = ((kb + (R)) <= K);                                     \
    x = act ? full : x;                                                     \
    if (CAP) capv = x;                                                      \
    if (RN) RENORM }

#define STEPS16F(P)                                                         \
    ggc = __builtin_amdgcn_exp2f(P##0 * LOG2E_F);                           \
    STEPF(EiA, 16, 1, P##1,  0, 0)                                          \
    STEPF(EiB, 32, 1, P##2,  0, 0)                                          \
    STEPF(EiA, 16, 1, P##3,  1, 0)                                          \
    STEPF(EiB, 32, 1, P##4,  0, 1)                                          \
    STEPF(EiA, 16, 1, P##5,  0, 0)                                          \
    STEPF(EiB, 32, 1, P##6,  0, 0)                                          \
    STEPF(EiA, 16, 1, P##7,  1, 0)                                          \
    STEPF(EiB, 32, 1, P##8,  0, 1)                                          \
    STEPF(EiA, 16, 1, P##9,  0, 0)                                          \
    STEPF(EiB, 32, 1, P##10, 0, 0)                                          \
    STEPF(EiA, 16, 1, P##11, 1, 0)                                          \
    STEPF(EiB, 32, 1, P##12, 0, 1)                                          \
    STEPF(EiA, 16, 1, P##13, 0, 0)                                          \
    STEPF(EiB, 32, 1, P##14, 0, 0)                                          \
    STEPF(EiA, 16, 1, P##15, 1, 0)                                          \
    STEPF(EiB, 32, 0, P##15, 0, 1)                                          \
    kb += 16;

#define STEPS16T(P)                                                         \
    ggc = __builtin_amdgcn_exp2f(P##0 * LOG2E_F);                           \
    STEPT(0,  EiA, 16, 1, P##1,  0, 0)                                      \
    STEPT(1,  EiB, 32, 1, P##2,  0, 0)                                      \
    STEPT(2,  EiA, 16, 1, P##3,  1, 0)                                      \
    STEPT(3,  EiB, 32, 1, P##4,  0, 1)                                      \
    STEPT(4,  EiA, 16, 1, P##5,  0, 0)                                      \
    STEPT(5,  EiB, 32, 1, P##6,  0, 0)                                      \
    STEPT(6,  EiA, 16, 1, P##7,  1, 0)                                      \
    STEPT(7,  EiB, 32, 1, P##8,  0, 1)                                      \
    STEPT(8,  EiA, 16, 1, P##9,  0, 0)                                      \
    STEPT(9,  EiB, 32, 1, P##10, 0, 0)                                      \
    STEPT(10, EiA, 16, 1, P##11, 1, 0)                                      \
    STEPT(11, EiB, 32, 1, P##12, 0, 1)                                      \
    STEPT(12, EiA, 16, 1, P##13, 0, 0)                                      \
    STEPT(13, EiB, 32, 1, P##14, 0, 0)                                      \
    STEPT(14, EiA, 16, 1, P##15, 1, 0)                                      \
    STEPT(15, EiB, 32, 0, P##15, 0, 1)                                      \
    kb += 16;

#define EI_SETUP2                                                           \
    float EiA[16], EiB[16];                                                 \
    {                                                                       \
        float tmax = -3.4e38f;                                              \
        _Pragma("unroll")                                                   \
        for (int t = 0; t < 16; ++t) {                                      \
            const int sg = ror_minus ? ((k15 - t) & 15) : ((k15 + t) & 15); \
            const int iA = 16 * ihA + sg;                                   \
            const int iB = 16 * ihB + sg;                                   \
            const float tvA = DIR ? trans[labA * Ln + iA]                   \
                                  : trans[iA * Ln + labA];                  \
            const float tvB = DIR ? trans[labB * Ln + iB]                   \
                                  : trans[iB * Ln + labB];                  \
            EiA[t] = tvA;  EiB[t] = tvB;                                    \
            tmax = fmaxf(tmax, tvA);    /* EA spans all of trans */         \
        }                                                                   \
        _Pragma("unroll")                                                   \
        for (int off = 1; off < 64; off <<= 1)                              \
            tmax = fmaxf(tmax, __shfl_xor(tmax, off));                      \
        tmax2 = tmax * LOG2E_F;                                             \
        _Pragma("unroll")                                                   \
        for (int t = 0; t < 16; ++t) {                                      \
            EiA[t] = __builtin_amdgcn_exp2f((EiA[t] - tmax) * LOG2E_F);     \
            EiB[t] = __builtin_amdgcn_exp2f((EiB[t] - tmax) * LOG2E_F);     \
        }                                                                   \
    }

// ---- chain body, DIR compile-time ------------------------------------------
template<int DIR>
__device__ __forceinline__ void chain_run(const float* __restrict__ logits,
                                          const float* __restrict__ trans,
                                          const int b, const int l,
                                          const int len,
                                          float* __restrict__ ws)
{
    const int k15 = l & 15;
    const int labB = l & 31;                        // phi label
    const int labA = (l & 15) | ((l >> 5) << 4);    // sigma label
    const int ihA  = (l >> 4) & 1;                  // row-half, phi-layout
    const int ihB  = (l >> 5) & 1;                  // row-half, sigma-layout

    const int m  = (len + 1) >> 1;
    const int K  = DIR ? (len - m) : (m - 1);
    const int nfull = K >> 4;
    const int ktail = K & 15;

    const float* xb = logits + (size_t)b * (Tn * Ln);

    const int w0 = __builtin_amdgcn_readfirstlane(
        __builtin_amdgcn_update_dpp(0, l, 0x121, 0xF, 0xF, true));
    const bool ror_minus = (w0 == 15);
    const bool uy32 = probe32sel(l);
    const bool ur16 = probe16sel(l);

    float tmax2;
    EI_SETUP2

    // init state in phi-layout
    float x, Minit;
    if constexpr (DIR == 0) {
        const float a0v = xb[labB] * LOG2E_F;
        float mx = a0v;
        #pragma unroll
        for (int off = 1; off < 64; off <<= 1)
            mx = fmaxf(mx, __shfl_xor(mx, off));
        x = __builtin_amdgcn_exp2f(a0v - mx);
        Minit = mx;
    } else {
        x = 1.0f;
        Minit = 0.0f;
    }
    float Mr = 0.0f;
    float capv = x;

    const unsigned col4O = (unsigned)(DIR ? labB : labA) * 4u;
    const unsigned col4E = (unsigned)(DIR ? labA : labB) * 4u;
    const int dtt = DIR ? -1 : 1;
    const int t0  = DIR ? (len - 1) : 1;

    float A0, A1, A2, A3, A4, A5, A6, A7;
    float A8, A9, A10, A11, A12, A13, A14, A15;
    float B0, B1, B2, B3, B4, B5, B6, B7;
    float B8, B9, B10, B11, B12, B13, B14, B15;

    float ggc = 1.0f;
    int kb = 1;

    ISSUE16(B, t0)
    WAITALL(B)
    COPY16(A, B)
    int tnext = t0 + 16 * dtt;

    for (int g = 0; g < nfull; ++g) {
        ISSUE16(B, tnext)
        tnext += 16 * dtt;
        __builtin_amdgcn_sched_barrier(0);
        STEPS16F(A)
        __builtin_amdgcn_sched_barrier(0);
        WAITALL(B)
        __builtin_amdgcn_sched_barrier(0);
        COPY16(A, B)
    }
    if (ktail) {
        STEPS16T(A)
    }

    asm volatile("s_waitcnt vmcnt(0)" ::: "memory");

    const float M = Minit + (float)K * tmax2 + Mr;

    // final layout depends on parity of K: even -> phi, odd -> sigma
    float* wsrow = ws + (size_t)(b * 2 + DIR) * 33;
    if (K & 1) {
        if ((l & 16) == 0) wsrow[labA] = x;
    } else {
        if (l < 32) wsrow[l] = x;
    }
    if (l == 0) wsrow[32] = M;
}

__global__ __launch_bounds__(64)
void crf_chain_kernel(const float* __restrict__ logits,
                      const float* __restrict__ trans,
                      const int* __restrict__ seq_lens,
                      float* __restrict__ ws)
{
    const int blk = blockIdx.x;
    const int b   = blk >> 1;
    const int dir = blk & 1;
    const int l   = threadIdx.x;

    int len = seq_lens[b];
    len = len < 1 ? 1 : (len > Tn ? Tn : len);
    len = __builtin_amdgcn_readfirstlane(len);   // uniform: scalar t-arithmetic

    if (dir == 0) chain_run<0>(logits, trans, b, l, len, ws);
    else          chain_run<1>(logits, trans, b, l, len, ws);
}

// ---- combine kernel: 256 threads (gather latency spread over 4 waves) ------
__global__ __launch_bounds__(256)
void crf_combine_kernel(const float* __restrict__ logits,
                        const float* __restrict__ trans,
                        const int* __restrict__ labels,
                        const int* __restrict__ seq_lens,
                        const float* __restrict__ ws,
                        float* __restrict__ out)
{
    const int b   = blockIdx.x;
    const int tid = threadIdx.x;

    int len = seq_lens[b];
    len = len < 1 ? 1 : (len > Tn ? Tn : len);

    const int*   lb = labels + (size_t)b * Tn;
    const float* xb = logits + (size_t)b * (Tn * Ln);

    float acc = 0.f;
    for (int t = tid; t < len; t += 256) {
        const int lt = lb[t];
        acc += xb[t * Ln + lt];
        if (t >= 1) acc += trans[lb[t - 1] * Ln + lt];
    }
    #pragma unroll
    for (int off = 1; off < 64; off <<= 1)
        acc += __shfl_xor(acc, off);

    __shared__ float wred[4];
    if ((tid & 63) == 0) wred[tid >> 6] = acc;
    __syncthreads();

    if (tid < 64) {
        const float gold = (wred[0] + wred[1]) + (wred[2] + wred[3]);
        const int j = tid & 31;
        const float* wf = ws + (size_t)(b * 2 + 0) * 33;
        const float* wb = ws + (size_t)(b * 2 + 1) * 33;
        float term = wf[j] * wb[j];
        #pragma unroll
        for (int off = 1; off < 32; off <<= 1)
            term += __shfl_xor(term, off);
        if (tid == 0) {
            const float Mf = wf[32], Mb = wb[32];
            out[b] = gold - (Mf + Mb + __builtin_amdgcn_logf(term)) * LN2_F;
        }
    }
}

extern "C" void kernel_launch(void* const* d_in, const int* in_sizes, int n_in,
                              void* d_out, int out_size, void* d_ws, size_t ws_size,
                              hipStream_t stream) {
    const float* logits   = (const float*)d_in[0];
    const float* trans    = (const float*)d_in[1];
    const int*   labels   = (const int*)d_in[2];
    const int*   seq_lens = (const int*)d_in[3];
    float* out = (float*)d_out;
    float* ws  = (float*)d_ws;    // 2048 * 33 floats = 270 KB

    crf_chain_kernel<<<Bn * 2, 64, 0, stream>>>(logits, trans, seq_lens, ws);
    crf_combine_kernel<<<Bn, 256, 0, stream>>>(logits, trans, labels, seq_lens, ws, out);
}